// Round 1
// baseline (75.993 us; speedup 1.0000x reference)
//
#include <hip/hip_runtime.h>

// r[b,n,o] = b2[o] + sum_h W2[h,o] * (1/N) * sum_m relu(u[b,m,h] + v[b,n,h])
//   u[m,h] =  x_m . W1[0:2,h] + y_m . W1[2:4,h]
//   v[n,h] = -x_n . W1[0:2,h] + y_n . W1[4:6,h] + b1[h]
//
// Grid: 256 blocks = B(8) x n-tiles(32 of 32 n each). Block: 512 threads (8 waves).
// LDS: u[b] tile = 1024 x 16 fp32 = 64 KB, reused after main loop for the
// cross-wave partial reduction + W2/b2/s_final scratch.
// Lane layout in main loop: g = lane&3 (4-channel group), nsub = lane>>2;
// each lane accumulates 2 n's (nsub, nsub+16). Wave w handles m in [w*128,(w+1)*128).
// LDS reads: 16 lanes per channel-group read the SAME address -> broadcast.

constexpr int NN = 1024;

__global__ __launch_bounds__(512, 2) void te_enc(
    const float* __restrict__ x_ctx,
    const float* __restrict__ y_ctx,
    const float* __restrict__ W1,
    const float* __restrict__ b1,
    const float* __restrict__ W2,
    const float* __restrict__ b2,
    float* __restrict__ out)
{
    __shared__ float lds[16384];   // 64 KB

    const int t    = threadIdx.x;
    const int wave = t >> 6;
    const int lane = t & 63;
    const int g    = lane & 3;     // channel group: channels 4g..4g+3
    const int nsub = lane >> 2;    // 0..15
    const int b    = blockIdx.x >> 5;
    const int n0   = (blockIdx.x & 31) << 5;

    // W1 chunks for this thread's 4 channels (rows 0..5 of [6][16] W1)
    const float4 w10 = *(const float4*)(W1 +  0 + 4*g);
    const float4 w11 = *(const float4*)(W1 + 16 + 4*g);
    const float4 w12 = *(const float4*)(W1 + 32 + 4*g);
    const float4 w13 = *(const float4*)(W1 + 48 + 4*g);
    const float4 w14 = *(const float4*)(W1 + 64 + 4*g);
    const float4 w15 = *(const float4*)(W1 + 80 + 4*g);
    const float4 b1c = *(const float4*)(b1 + 4*g);

    // ---- Phase A: u[m][0..15] for all m of this batch -> LDS ----
    // thread t handles (mm = t>>2, g = t&3); writes are lane-contiguous (addr = 4*lane)
    {
        const int mm = t >> 2;     // 0..127
        #pragma unroll
        for (int rep = 0; rep < 8; ++rep) {
            const int m = rep * 128 + mm;
            const float2 xm = *(const float2*)(x_ctx + (b * NN + m) * 2);
            const float2 ym = *(const float2*)(y_ctx + (b * NN + m) * 2);
            float4 u;
            u.x = xm.x*w10.x + xm.y*w11.x + ym.x*w12.x + ym.y*w13.x;
            u.y = xm.x*w10.y + xm.y*w11.y + ym.x*w12.y + ym.y*w13.y;
            u.z = xm.x*w10.z + xm.y*w11.z + ym.x*w12.z + ym.y*w13.z;
            u.w = xm.x*w10.w + xm.y*w11.w + ym.x*w12.w + ym.y*w13.w;
            *(float4*)(lds + m * 16 + 4 * g) = u;
        }
    }

    // ---- v for this lane's two n's (registers only) ----
    const int n1 = n0 + nsub;
    const int n2 = n1 + 16;
    float4 v1, v2;
    {
        const float2 xn = *(const float2*)(x_ctx + (b * NN + n1) * 2);
        const float2 yn = *(const float2*)(y_ctx + (b * NN + n1) * 2);
        v1.x = b1c.x - xn.x*w10.x - xn.y*w11.x + yn.x*w14.x + yn.y*w15.x;
        v1.y = b1c.y - xn.x*w10.y - xn.y*w11.y + yn.x*w14.y + yn.y*w15.y;
        v1.z = b1c.z - xn.x*w10.z - xn.y*w11.z + yn.x*w14.z + yn.y*w15.z;
        v1.w = b1c.w - xn.x*w10.w - xn.y*w11.w + yn.x*w14.w + yn.y*w15.w;
    }
    {
        const float2 xn = *(const float2*)(x_ctx + (b * NN + n2) * 2);
        const float2 yn = *(const float2*)(y_ctx + (b * NN + n2) * 2);
        v2.x = b1c.x - xn.x*w10.x - xn.y*w11.x + yn.x*w14.x + yn.y*w15.x;
        v2.y = b1c.y - xn.x*w10.y - xn.y*w11.y + yn.x*w14.y + yn.y*w15.y;
        v2.z = b1c.z - xn.x*w10.z - xn.y*w11.z + yn.x*w14.z + yn.y*w15.z;
        v2.w = b1c.w - xn.x*w10.w - xn.y*w11.w + yn.x*w14.w + yn.y*w15.w;
    }

    __syncthreads();

    // ---- Phase B: main loop, wave 'wave' covers 128 m's ----
    float4 s1 = {0.f, 0.f, 0.f, 0.f};
    float4 s2 = {0.f, 0.f, 0.f, 0.f};
    const float* up = lds + wave * 2048 + 4 * g;   // (wave*128)*16 + 4g
    #pragma unroll 4
    for (int i = 0; i < 128; ++i) {
        const float4 u = *(const float4*)(up + i * 16);
        float ax, ay, az, aw;
        ax = fmaxf(u.x + v1.x, 0.f); s1.x += ax;
        ay = fmaxf(u.y + v1.y, 0.f); s1.y += ay;
        az = fmaxf(u.z + v1.z, 0.f); s1.z += az;
        aw = fmaxf(u.w + v1.w, 0.f); s1.w += aw;
        ax = fmaxf(u.x + v2.x, 0.f); s2.x += ax;
        ay = fmaxf(u.y + v2.y, 0.f); s2.y += ay;
        az = fmaxf(u.z + v2.z, 0.f); s2.z += az;
        aw = fmaxf(u.w + v2.w, 0.f); s2.w += aw;
    }

    __syncthreads();   // everyone done reading u; LDS is now reusable

    // ---- Phase C: spill partials; stage W2/b2 ----
    // partials occupy lds[0 .. 4095] (floats); W2 at 4096..4351; b2 at 4352..4367;
    // s_final at 4368..4879
    {
        const int base = ((wave * 64 + lane) * 2) * 4;
        *(float4*)(lds + base)     = s1;
        *(float4*)(lds + base + 4) = s2;
    }
    if (t < 256) lds[4096 + t] = W2[t];
    if (t < 16)  lds[4352 + t] = b2[t];
    __syncthreads();

    // ---- Phase D: reduce over the 8 waves, apply 1/N ----
    if (t < 128) {
        const int l = t >> 1;      // lane id in the partial layout
        const int p = t & 1;       // which n-set
        float4 acc = {0.f, 0.f, 0.f, 0.f};
        #pragma unroll
        for (int w = 0; w < 8; ++w) {
            const float4 q = *(const float4*)(lds + ((w * 64 + l) * 2 + p) * 4);
            acc.x += q.x; acc.y += q.y; acc.z += q.z; acc.w += q.w;
        }
        const float inv = 1.0f / 1024.0f;
        acc.x *= inv; acc.y *= inv; acc.z *= inv; acc.w *= inv;
        const int nsf = (l >> 2) + 16 * p;   // 0..31
        const int gf  = l & 3;
        *(float4*)(lds + 4368 + nsf * 16 + gf * 4) = acc;
    }
    __syncthreads();

    // ---- Phase E: W2 epilogue, coalesced store ----
    {
        const int j = t >> 4;      // 0..31 (n within tile)
        const int o = t & 15;      // output channel
        const float* sf = lds + 4368 + j * 16;
        const float* w2 = lds + 4096;
        float acc = lds[4352 + o];
        #pragma unroll
        for (int h = 0; h < 16; ++h)
            acc += sf[h] * w2[h * 16 + o];
        out[(b * NN + n0 + j) * 16 + o] = acc;
    }
}

extern "C" void kernel_launch(void* const* d_in, const int* in_sizes, int n_in,
                              void* d_out, int out_size, void* d_ws, size_t ws_size,
                              hipStream_t stream) {
    const float* x_ctx = (const float*)d_in[0];
    const float* y_ctx = (const float*)d_in[1];
    // d_in[2] = x_trg : unused by the reference computation
    const float* W1 = (const float*)d_in[3];
    const float* b1 = (const float*)d_in[4];
    const float* W2 = (const float*)d_in[5];
    const float* b2 = (const float*)d_in[6];
    float* out = (float*)d_out;

    te_enc<<<256, 512, 0, stream>>>(x_ctx, y_ctx, W1, b1, W2, b2, out);
}

// Round 2
// 75.753 us; speedup vs baseline: 1.0032x; 1.0032x over previous
//
#include <hip/hip_runtime.h>

// r[b,n,o] = b2[o] + sum_h W2[h,o] * (1/N) * sum_m relu(u[b,m,h] + v[b,n,h])
//   u[m,h] =  x_m . W1[0:2,h] + y_m . W1[2:4,h]
//   v[n,h] = -x_n . W1[0:2,h] + y_n . W1[4:6,h] + b1[h]
//
// relu trick: sum_m relu(u+v) = 0.5*( sum_m |u+v| + Su + N*v ),
//   Su[h] = sum_m u[m,h] = Sxx*W1[0,h]+Sxy*W1[1,h]+Syx*W1[2,h]+Syy*W1[3,h]
// -> main loop is 2 VALU ops per (m,n,h): v_add + v_add(abs()) instead of 3.
//
// Grid: 256 blocks = B(8) x n-tiles(32 of 32 n each). Block: 512 threads (8 waves).
// LDS: u[b] = 1024x16 fp32 = 64 KB (phases A,B); reused post-loop for reduction.
// Main-loop lane layout: g = lane&3 (channel group 4g..4g+3), nsub = lane>>2;
// lane accumulates n = n0+nsub and n0+nsub+16. Wave w covers m in [w*128,(w+1)*128).
// LDS reads broadcast: 16 lanes per g read the same 16B address.

constexpr int NN = 1024;

__global__ __launch_bounds__(512, 2) void te_enc(
    const float* __restrict__ x_ctx,
    const float* __restrict__ y_ctx,
    const float* __restrict__ W1,
    const float* __restrict__ b1,
    const float* __restrict__ W2,
    const float* __restrict__ b2,
    float* __restrict__ out)
{
    __shared__ float lds[16384];   // 64 KB

    const int t    = threadIdx.x;
    const int wave = t >> 6;
    const int lane = t & 63;
    const int g    = lane & 3;
    const int nsub = lane >> 2;
    const int b    = blockIdx.x >> 5;
    const int n0   = (blockIdx.x & 31) << 5;

    // W1 chunks for this thread's 4 channels (rows 0..5 of [6][16] W1)
    const float4 w10 = *(const float4*)(W1 +  0 + 4*g);
    const float4 w11 = *(const float4*)(W1 + 16 + 4*g);
    const float4 w12 = *(const float4*)(W1 + 32 + 4*g);
    const float4 w13 = *(const float4*)(W1 + 48 + 4*g);
    const float4 w14 = *(const float4*)(W1 + 64 + 4*g);
    const float4 w15 = *(const float4*)(W1 + 80 + 4*g);
    const float4 b1c = *(const float4*)(b1 + 4*g);

    // ---- Phase A: u[m][0..15] for all m of this batch -> LDS ----
    {
        const int mm = t >> 2;     // 0..127
        #pragma unroll
        for (int rep = 0; rep < 8; ++rep) {
            const int m = rep * 128 + mm;
            const float2 xm = *(const float2*)(x_ctx + (b * NN + m) * 2);
            const float2 ym = *(const float2*)(y_ctx + (b * NN + m) * 2);
            float4 u;
            u.x = xm.x*w10.x + xm.y*w11.x + ym.x*w12.x + ym.y*w13.x;
            u.y = xm.x*w10.y + xm.y*w11.y + ym.x*w12.y + ym.y*w13.y;
            u.z = xm.x*w10.z + xm.y*w11.z + ym.x*w12.z + ym.y*w13.z;
            u.w = xm.x*w10.w + xm.y*w11.w + ym.x*w12.w + ym.y*w13.w;
            *(float4*)(lds + m * 16 + 4 * g) = u;
        }
    }

    // ---- v for this lane's two n's ----
    const int n1 = n0 + nsub;
    const int n2 = n1 + 16;
    float4 v1, v2;
    {
        const float2 xn = *(const float2*)(x_ctx + (b * NN + n1) * 2);
        const float2 yn = *(const float2*)(y_ctx + (b * NN + n1) * 2);
        v1.x = b1c.x - xn.x*w10.x - xn.y*w11.x + yn.x*w14.x + yn.y*w15.x;
        v1.y = b1c.y - xn.x*w10.y - xn.y*w11.y + yn.x*w14.y + yn.y*w15.y;
        v1.z = b1c.z - xn.x*w10.z - xn.y*w11.z + yn.x*w14.z + yn.y*w15.z;
        v1.w = b1c.w - xn.x*w10.w - xn.y*w11.w + yn.x*w14.w + yn.y*w15.w;
    }
    {
        const float2 xn = *(const float2*)(x_ctx + (b * NN + n2) * 2);
        const float2 yn = *(const float2*)(y_ctx + (b * NN + n2) * 2);
        v2.x = b1c.x - xn.x*w10.x - xn.y*w11.x + yn.x*w14.x + yn.y*w15.x;
        v2.y = b1c.y - xn.x*w10.y - xn.y*w11.y + yn.x*w14.y + yn.y*w15.y;
        v2.z = b1c.z - xn.x*w10.z - xn.y*w11.z + yn.x*w14.z + yn.y*w15.z;
        v2.w = b1c.w - xn.x*w10.w - xn.y*w11.w + yn.x*w14.w + yn.y*w15.w;
    }

    __syncthreads();

    // ---- Phase B: main loop, |u+v| accumulation ----
    float4 s1 = {0.f, 0.f, 0.f, 0.f};
    float4 s2 = {0.f, 0.f, 0.f, 0.f};
    const float* up = lds + wave * 2048 + 4 * g;
    #pragma unroll 4
    for (int i = 0; i < 128; ++i) {
        const float4 u = *(const float4*)(up + i * 16);
        s1.x += fabsf(u.x + v1.x);
        s1.y += fabsf(u.y + v1.y);
        s1.z += fabsf(u.z + v1.z);
        s1.w += fabsf(u.w + v1.w);
        s2.x += fabsf(u.x + v2.x);
        s2.y += fabsf(u.y + v2.y);
        s2.z += fabsf(u.z + v2.z);
        s2.w += fabsf(u.w + v2.w);
    }

    __syncthreads();   // u no longer needed; LDS reusable

    // ---- Phase C: spill partials + stage epilogue data ----
    // LDS float map: [0,4096) abs partials; [4096,4608) v[32][16];
    // [4608,4864) W2; [4864,4880) b2; [4880,4944) W1 rows 0..3;
    // [4944,4976) batch-sum partials [8][4]; [4976,5488) s_final[32][16]
    {
        const int base = ((wave * 64 + lane) * 2) * 4;
        *(float4*)(lds + base)     = s1;
        *(float4*)(lds + base + 4) = s2;
    }
    if (wave == 0) {
        *(float4*)(lds + 4096 + n1 % 32 * 0 + (nsub)      * 16 + 4 * g) = v1;
        *(float4*)(lds + 4096 + (nsub + 16) * 16 + 4 * g) = v2;
    }
    if (t < 256) lds[4608 + t] = W2[t];
    if (t < 16)  lds[4864 + t] = b2[t];
    if (t < 64)  lds[4880 + t] = W1[t];   // rows 0..3

    // batch sums: thread t covers m = 2t, 2t+1 via float4
    {
        const float4 xa = *(const float4*)(x_ctx + b * 2048 + t * 4);
        const float4 ya = *(const float4*)(y_ctx + b * 2048 + t * 4);
        float sxx = xa.x + xa.z;
        float sxy = xa.y + xa.w;
        float syx = ya.x + ya.z;
        float syy = ya.y + ya.w;
        #pragma unroll
        for (int off = 32; off > 0; off >>= 1) {
            sxx += __shfl_down(sxx, off);
            sxy += __shfl_down(sxy, off);
            syx += __shfl_down(syx, off);
            syy += __shfl_down(syy, off);
        }
        if (lane == 0) {
            float4 bs = {sxx, sxy, syx, syy};
            *(float4*)(lds + 4944 + wave * 4) = bs;
        }
    }
    __syncthreads();

    // ---- Phase D: reduce 8 waves, apply relu identity + 1/N ----
    if (t < 128) {
        const int l = t >> 1;
        const int p = t & 1;
        float4 acc = {0.f, 0.f, 0.f, 0.f};
        #pragma unroll
        for (int w = 0; w < 8; ++w) {
            const float4 q = *(const float4*)(lds + ((w * 64 + l) * 2 + p) * 4);
            acc.x += q.x; acc.y += q.y; acc.z += q.z; acc.w += q.w;
        }
        float4 bs = {0.f, 0.f, 0.f, 0.f};
        #pragma unroll
        for (int w = 0; w < 8; ++w) {
            const float4 q = *(const float4*)(lds + 4944 + w * 4);
            bs.x += q.x; bs.y += q.y; bs.z += q.z; bs.w += q.w;
        }
        const int nsf = (l >> 2) + 16 * p;
        const int gf  = l & 3;
        const int c   = 4 * gf;
        float4 su;
        su.x = bs.x*lds[4880+c  ] + bs.y*lds[4896+c  ] + bs.z*lds[4912+c  ] + bs.w*lds[4928+c  ];
        su.y = bs.x*lds[4880+c+1] + bs.y*lds[4896+c+1] + bs.z*lds[4912+c+1] + bs.w*lds[4928+c+1];
        su.z = bs.x*lds[4880+c+2] + bs.y*lds[4896+c+2] + bs.z*lds[4912+c+2] + bs.w*lds[4928+c+2];
        su.w = bs.x*lds[4880+c+3] + bs.y*lds[4896+c+3] + bs.z*lds[4912+c+3] + bs.w*lds[4928+c+3];
        const float4 vv = *(const float4*)(lds + 4096 + nsf * 16 + c);
        const float k = 0.5f / 1024.0f;
        float4 r;
        r.x = (acc.x + su.x) * k + 0.5f * vv.x;
        r.y = (acc.y + su.y) * k + 0.5f * vv.y;
        r.z = (acc.z + su.z) * k + 0.5f * vv.z;
        r.w = (acc.w + su.w) * k + 0.5f * vv.w;
        *(float4*)(lds + 4976 + nsf * 16 + c) = r;
    }
    __syncthreads();

    // ---- Phase E: W2 epilogue, coalesced store ----
    {
        const int j = t >> 4;      // n within tile
        const int o = t & 15;      // output channel
        const float* sf = lds + 4976 + j * 16;
        const float* w2 = lds + 4608;
        float acc = lds[4864 + o];
        #pragma unroll
        for (int h = 0; h < 16; ++h)
            acc += sf[h] * w2[h * 16 + o];
        out[(b * NN + n0 + j) * 16 + o] = acc;
    }
}

extern "C" void kernel_launch(void* const* d_in, const int* in_sizes, int n_in,
                              void* d_out, int out_size, void* d_ws, size_t ws_size,
                              hipStream_t stream) {
    const float* x_ctx = (const float*)d_in[0];
    const float* y_ctx = (const float*)d_in[1];
    // d_in[2] = x_trg : unused by the reference computation
    const float* W1 = (const float*)d_in[3];
    const float* b1 = (const float*)d_in[4];
    const float* W2 = (const float*)d_in[5];
    const float* b2 = (const float*)d_in[6];
    float* out = (float*)d_out;

    te_enc<<<256, 512, 0, stream>>>(x_ctx, y_ctx, W1, b1, W2, b2, out);
}